// Round 1
// 938.953 us; speedup vs baseline: 1.1261x; 1.1261x over previous
//
#include <hip/hip_runtime.h>

typedef unsigned short u16;
typedef short bf16x8 __attribute__((ext_vector_type(8)));
typedef float f32x4 __attribute__((ext_vector_type(4)));

__device__ __forceinline__ u16 f2bf(float f) {
    unsigned u = __float_as_uint(f);
    u = (u + 0x7fffu + ((u >> 16) & 1u)) >> 16;
    return (u16)u;
}
__device__ __forceinline__ float bf2f(u16 h) {
    return __uint_as_float(((unsigned)h) << 16);
}
// cheap round-to-nearest pack (a -> low16, b -> high16)
__device__ __forceinline__ unsigned pk2c(float a, float b) {
    return ((__float_as_uint(a) + 0x8000u) >> 16) |
           ((__float_as_uint(b) + 0x8000u) & 0xffff0000u);
}
__device__ __forceinline__ void async16(void* lds, const void* g) {
    __builtin_amdgcn_global_load_lds(
        (const __attribute__((address_space(1))) void*)g,
        (__attribute__((address_space(3))) void*)lds, 16, 0, 0);
}

union U4BF8 { uint4 u; bf16x8 v; };

// ---------------------------------------------------------------------------
// transpose_cvt: dst[c][r] = bf16(src[r][c]); 64x64 LDS tiles, both sides
// coalesced. grid = (C/64, R/64).
// ---------------------------------------------------------------------------
__global__ __launch_bounds__(256) void transpose_cvt(
    const float* __restrict__ src, u16* __restrict__ dst, int R, int C)
{
    __shared__ float tile[64][65];
    const int t = threadIdx.x;
    const int lane = t & 63, wave = t >> 6;
    const int c0 = blockIdx.x * 64, r0 = blockIdx.y * 64;
#pragma unroll
    for (int rr = 0; rr < 16; ++rr) {
        int rl = rr * 4 + wave;
        tile[rl][lane] = src[(size_t)(r0 + rl) * C + c0 + lane];
    }
    __syncthreads();
#pragma unroll
    for (int rr = 0; rr < 16; ++rr) {
        int cl = rr * 4 + wave;
        dst[(size_t)(c0 + cl) * R + r0 + lane] = f2bf(tile[lane][cl]);
    }
}

// ---------------------------------------------------------------------------
// prep_small:
//  blocks 0..7 : Wsr[256][6]  = Ws @ Wr (32 d-rows per block)
//  blocks 8..15: Wvr[h][256][6] = Wv_h @ Wr_h (32 d-rows per block, all 8
//                heads; lane-group os==head handles its own 64-col slice)
//  block 16    : mask M[dst][src] = ln(mult) / -1e30; out[b][:] pre-written
//                with c0 = (bs+bv)@Wr + br for all 1024 b.
// ---------------------------------------------------------------------------
__global__ __launch_bounds__(256) void prep_small(
    const int* __restrict__ ei, const float* __restrict__ Wsf,
    const float* __restrict__ Wvf, const float* __restrict__ Wr,
    const float* __restrict__ bsf, const float* __restrict__ bvf,
    const float* __restrict__ brf, float* __restrict__ Mm,
    float* __restrict__ Wsr, float* __restrict__ Wvr,
    float* __restrict__ out)
{
    int t = threadIdx.x, bx = blockIdx.x;
    if (bx < 8) {
        int d = bx * 32 + (t >> 3);
        int os = t & 7;
        float a[6] = {0.f, 0.f, 0.f, 0.f, 0.f, 0.f};
        for (int i = 0; i < 64; ++i) {
            int o = os * 64 + i;
            float w = Wsf[(size_t)d * 512 + o];
#pragma unroll
            for (int j = 0; j < 6; ++j) a[j] += w * Wr[o * 6 + j];
        }
#pragma unroll
        for (int j = 0; j < 6; ++j) {
            a[j] += __shfl_xor(a[j], 1);
            a[j] += __shfl_xor(a[j], 2);
            a[j] += __shfl_xor(a[j], 4);
        }
        if (os == 0) {
#pragma unroll
            for (int j = 0; j < 6; ++j) Wsr[d * 6 + j] = a[j];
        }
    } else if (bx < 16) {
        // Wvr: head h = lane-group (t&7); o-range = h*64..h*64+63
        int d = (bx - 8) * 32 + (t >> 3);
        int hh = t & 7;
        float a[6] = {0.f, 0.f, 0.f, 0.f, 0.f, 0.f};
        for (int i = 0; i < 64; ++i) {
            int o = hh * 64 + i;
            float w = Wvf[(size_t)d * 512 + o];
#pragma unroll
            for (int j = 0; j < 6; ++j) a[j] += w * Wr[o * 6 + j];
        }
#pragma unroll
        for (int j = 0; j < 6; ++j) Wvr[(size_t)(hh * 256 + d) * 6 + j] = a[j];
    } else {
        __shared__ int cnt[4096];
        __shared__ float c6[6];
        for (int i = t; i < 4096; i += 256) cnt[i] = 0;
        if (t < 6) c6[t] = 0.f;
        __syncthreads();
        for (int e = t; e < 1024; e += 256) {
            int s = ei[e];
            int d = ei[1024 + e];
            atomicAdd(&cnt[d * 64 + s], 1);
        }
        __syncthreads();
        for (int i = t; i < 4096; i += 256) {
            int c = cnt[i];
            Mm[i] = (c > 0) ? logf((float)c) : -1e30f;
        }
        // c0 = (bs+bv)@Wr
        float a[6] = {0.f, 0.f, 0.f, 0.f, 0.f, 0.f};
        for (int o = t; o < 512; o += 256) {
            float bb = bsf[o] + bvf[o];
#pragma unroll
            for (int j = 0; j < 6; ++j) a[j] += bb * Wr[o * 6 + j];
        }
#pragma unroll
        for (int j = 0; j < 6; ++j) {
            float v = a[j];
            for (int off = 32; off; off >>= 1) v += __shfl_down(v, off);
            if ((t & 63) == 0) atomicAdd(&c6[j], v);
        }
        __syncthreads();
        // pre-write out[b][:] = c0 + br for all b (attn atomically adds)
        for (int i = t; i < 6144; i += 256) {
            int j = i % 6;
            out[i] = c6[j] + brf[j];
        }
    }
}

// ---------------------------------------------------------------------------
// gemm1: Xp_bf16[65536][256] = bf16(X[65536][2048]) @ bf16(Wp) + bp
// Tile 64(M) x 256(N=all) x 32(K). ALL staging via global_load_lds (async
// DMA, no VGPR round trip, no mid-loop vmem waits). A stored fp32 with
// 144-B rows (9 chunks; chunk 8 = dup of chunk 0 -> 2-way-only bank alias).
// B from WpT with 80-B rows (5 chunks, chunk 4 dup). 4 waves, each owns
// 16 rows x 256 cols (acc = 16 x f32x4 = 64 VGPR). Small LDS (29.7 KB) ->
// 4-5 resident blocks/CU stagger the per-iteration vmcnt drain.
// ---------------------------------------------------------------------------
__global__ __launch_bounds__(256, 4) void gemm1(const float* __restrict__ X,
                                                const u16* __restrict__ WpT,
                                                const float* __restrict__ bp,
                                                u16* __restrict__ Xp)
{
    __shared__ alignas(16) float As[64 * 36];   // 9216 B
    __shared__ alignas(16) u16   Bs[256 * 40];  // 20480 B
    const int t = threadIdx.x;
    const int lane = t & 63, wave = t >> 6;
    const int lr = lane & 15, q8 = lane >> 4;
    const int m0 = blockIdx.x * 64;

    // --- per-lane DMA source pointers (row/part via exact magic division) ---
    // A: 576 chunks of 16 B, c -> row=c/9, part=c%9 (part 8 duplicates part 0)
    const int ca0 = t, ca1 = 256 + t, ca2 = 512 + lane;
    const int ra0 = (ca0 * 7282) >> 16, pa0 = ca0 - ra0 * 9;
    const int ra1 = (ca1 * 7282) >> 16, pa1 = ca1 - ra1 * 9;
    const int ra2 = (ca2 * 7282) >> 16, pa2 = ca2 - ra2 * 9;
    const float* pA0 = X + (size_t)(m0 + ra0) * 2048 + (pa0 == 8 ? 0 : pa0 * 4);
    const float* pA1 = X + (size_t)(m0 + ra1) * 2048 + (pa1 == 8 ? 0 : pa1 * 4);
    const float* pA2 = X + (size_t)(m0 + ra2) * 2048 + (pa2 == 8 ? 0 : pa2 * 4);
    // B: 1280 chunks of 16 B, c -> n=c/5, part=c%5 (part 4 duplicates part 0)
    const u16* pB[5];
#pragma unroll
    for (int i = 0; i < 5; ++i) {
        int c = i * 256 + t;
        int n = (c * 13108) >> 16;
        int prt = c - n * 5;
        pB[i] = WpT + (size_t)n * 2048 + (prt == 4 ? 0 : prt * 8);
    }

    const f32x4 z4 = {0.f, 0.f, 0.f, 0.f};
    f32x4 acc[16];
#pragma unroll
    for (int j = 0; j < 16; ++j) acc[j] = z4;

    const int arow = (wave * 16 + lr) * 36 + q8 * 8;

    for (int kk = 0; kk < 64; ++kk) {
        const int k0 = kk * 32;
        // ---- async DMA staging (only waits are at the barrier) ----
        async16(&As[(size_t)ca0 * 4], pA0 + k0);
        async16(&As[(size_t)ca1 * 4], pA1 + k0);
        if (wave == 0) async16(&As[(size_t)ca2 * 4], pA2 + k0);
#pragma unroll
        for (int i = 0; i < 5; ++i)
            async16(&Bs[(size_t)(i * 256 + t) * 8], pB[i] + k0);
        __syncthreads();
        // ---- compute: 1 A-frag (fp32->bf16 pack), 16 B-frags, 16 MFMA ----
        const float4 af0 = *(const float4*)&As[arow];
        const float4 af1 = *(const float4*)&As[arow + 4];
        U4BF8 ua;
        ua.u.x = pk2c(af0.x, af0.y);
        ua.u.y = pk2c(af0.z, af0.w);
        ua.u.z = pk2c(af1.x, af1.y);
        ua.u.w = pk2c(af1.z, af1.w);
        const bf16x8 a = ua.v;
#pragma unroll
        for (int j = 0; j < 16; ++j) {
            const bf16x8 b = *(const bf16x8*)&Bs[(j * 16 + lr) * 40 + q8 * 8];
            acc[j] = __builtin_amdgcn_mfma_f32_16x16x32_bf16(a, b, acc[j], 0, 0, 0);
        }
        __syncthreads();
    }

#pragma unroll
    for (int j = 0; j < 16; ++j) {
        const int col = j * 16 + lr;
        const float bias = bp[col];
#pragma unroll
        for (int r = 0; r < 4; ++r) {
            int row = m0 + wave * 16 + q8 * 4 + r;
            Xp[(size_t)row * 256 + col] = f2bf(acc[j][r] + bias);
        }
    }
}

// ---------------------------------------------------------------------------
// attn: one block per (b,h). Stage Xp[b] -> LDS; Q,K via MFMA (B from L2);
// S = qk^T/8 + mask (MFMA); in-register softmax; colsum(Pn)/64 -> w.
// V is NEVER computed: out_h = (w @ V_h) @ Wr_h = (w @ Xp) @ (Wv_h @ Wr_h),
// so we form t[d] = sum_src w[src]*Xp[b][src][d] (64 conflict-free scalar
// LDS reads/thread) and contract with the precomputed Wvr_h [256x6].
// h==0 block also folds in the skip path: xbar accumulates for free in the
// same loop; out[b] += t@Wvr_h + (h==0)*xbar@Wsr  (out pre-set to c0).
// LDS 51.5 KB -> 3 blocks/CU (was 2).
// ---------------------------------------------------------------------------
__global__ __launch_bounds__(256, 3) void attn(
    const u16* __restrict__ Xp, const u16* __restrict__ WT,
    const float* __restrict__ Mm, const float* __restrict__ bq,
    const float* __restrict__ bk, const float* __restrict__ Wvr,
    const float* __restrict__ Wsr, float* __restrict__ out)
{
    __shared__ alignas(16) u16 Xs[64 * 256];
    __shared__ alignas(16) u16 Qs[64 * 72];
    __shared__ alignas(16) u16 Ks[64 * 72];
    __shared__ float w_l[64];
    __shared__ float acc6[6];

    const int t = threadIdx.x;
    const int lane = t & 63, wave = t >> 6;
    const int lr = lane & 15, q8 = lane >> 4;
    const int bh = blockIdx.x, b = bh >> 3, h = bh & 7;
    const f32x4 z4 = {0.f, 0.f, 0.f, 0.f};

    if (t < 64) w_l[t] = 0.f;
    if (t < 6) acc6[t] = 0.f;

    {   // stage Xp[b] -> Xs, XOR-swizzled 16B chunks
        const u16* xg = Xp + (size_t)b * 16384;
#pragma unroll
        for (int it = 0; it < 8; ++it) {
            int c = it * 256 + t;
            int row = c >> 5, s = c & 31;
            int g = (s & 24) | ((s & 7) ^ (row & 7));
            async16(&Xs[(it * 256 + wave * 64) * 8], xg + (size_t)row * 256 + g * 8);
        }
    }
    __syncthreads();

    // --- QK GEMM: 8 col-tiles of 16 (q0-3, k4-7); wave owns 2
    f32x4 acc[2][4];
#pragma unroll
    for (int jt = 0; jt < 2; ++jt)
#pragma unroll
        for (int i = 0; i < 4; ++i) acc[jt][i] = z4;
    const int jj0 = wave * 2;
#pragma unroll 2
    for (int kk = 0; kk < 8; ++kk) {
        bf16x8 af[4];
#pragma unroll
        for (int i = 0; i < 4; ++i) {
            int m = i * 16 + lr;
            int g = kk * 4 + q8;
            int s = (g & 24) | ((g & 7) ^ (m & 7));
            af[i] = *(const bf16x8*)&Xs[m * 256 + s * 8];
        }
#pragma unroll
        for (int jt = 0; jt < 2; ++jt) {
            int jj = jj0 + jt, sec = jj >> 2;
            int r = sec * 512 + h * 64 + (jj & 3) * 16 + lr;
            bf16x8 bfv = *(const bf16x8*)(WT + (size_t)r * 256 + kk * 32 + q8 * 8);
#pragma unroll
            for (int i = 0; i < 4; ++i)
                acc[jt][i] = __builtin_amdgcn_mfma_f32_16x16x32_bf16(
                    af[i], bfv, acc[jt][i], 0, 0, 0);
        }
    }
    // epilogue -> LDS (pad 72); q scaled 1/8 w/ bias, k w/ bias
#pragma unroll
    for (int jt = 0; jt < 2; ++jt) {
        int jj = jj0 + jt, sec = jj >> 2;
        int colh = (jj & 3) * 16 + lr;
        float bias = (sec == 0) ? bq[h * 64 + colh] : bk[h * 64 + colh];
#pragma unroll
        for (int i = 0; i < 4; ++i)
#pragma unroll
            for (int r2 = 0; r2 < 4; ++r2) {
                int row = i * 16 + q8 * 4 + r2;
                float v = acc[jt][i][r2] + bias;
                if (sec == 0) Qs[row * 72 + colh] = f2bf(v * 0.125f);
                else          Ks[row * 72 + colh] = f2bf(v);
            }
    }
    __syncthreads();

    // --- S-MFMA: wave owns dst rows wave*16..+15
    f32x4 sacc[4];
#pragma unroll
    for (int j = 0; j < 4; ++j) sacc[j] = z4;
#pragma unroll
    for (int k2 = 0; k2 < 2; ++k2) {
        bf16x8 aq = *(const bf16x8*)&Qs[(wave * 16 + lr) * 72 + k2 * 32 + q8 * 8];
#pragma unroll
        for (int j = 0; j < 4; ++j) {
            bf16x8 bk8 = *(const bf16x8*)&Ks[(j * 16 + lr) * 72 + k2 * 32 + q8 * 8];
            sacc[j] = __builtin_amdgcn_mfma_f32_16x16x32_bf16(aq, bk8, sacc[j], 0, 0, 0);
        }
    }
    // --- mask + in-register softmax (rows in C layout)
    const int dst0 = wave * 16 + q8 * 4;
    float p[4][4];
#pragma unroll
    for (int r2 = 0; r2 < 4; ++r2) {
        float m = -1e38f;
#pragma unroll
        for (int j = 0; j < 4; ++j) {
            sacc[j][r2] += Mm[(dst0 + r2) * 64 + j * 16 + lr];
            m = fmaxf(m, sacc[j][r2]);
        }
        m = fmaxf(m, __shfl_xor(m, 1));
        m = fmaxf(m, __shfl_xor(m, 2));
        m = fmaxf(m, __shfl_xor(m, 4));
        m = fmaxf(m, __shfl_xor(m, 8));
        bool dead = (m < -1e29f);
        float rs = 0.f;
#pragma unroll
        for (int j = 0; j < 4; ++j) {
            float pv = dead ? 0.f : __expf(sacc[j][r2] - m);
            p[j][r2] = pv;
            rs += pv;
        }
        rs += __shfl_xor(rs, 1);
        rs += __shfl_xor(rs, 2);
        rs += __shfl_xor(rs, 4);
        rs += __shfl_xor(rs, 8);
        float sc = 1.0f / (rs + 1e-16f) * (1.0f / 64.0f);
#pragma unroll
        for (int j = 0; j < 4; ++j) p[j][r2] *= sc;
    }
    // --- column sums -> w_l
#pragma unroll
    for (int j = 0; j < 4; ++j) {
        float cw = p[j][0] + p[j][1] + p[j][2] + p[j][3];
        cw += __shfl_xor(cw, 16);
        cw += __shfl_xor(cw, 32);
        if (lane < 16) atomicAdd(&w_l[j * 16 + lr], cw);
    }
    __syncthreads();

    // --- t[d] = sum_src w[src] * Xs[src][d]; xbar rides along (h==0 skip)
    float td = 0.f, xb = 0.f;
    const int gch = t >> 3, off = t & 7;
#pragma unroll 8
    for (int src = 0; src < 64; ++src) {
        int s = (gch & 24) | ((gch & 7) ^ (src & 7));
        float xv = bf2f(Xs[(src * 32 + s) * 8 + off]);
        td = fmaf(w_l[src], xv, td);
        xb += xv;
    }
    float o[6];
    const float* wv = Wvr + (size_t)(h * 256 + t) * 6;
#pragma unroll
    for (int j = 0; j < 6; ++j) o[j] = td * wv[j];
    if (h == 0) {
        float xm = xb * (1.0f / 64.0f);
        const float* ws6 = Wsr + t * 6;
#pragma unroll
        for (int j = 0; j < 6; ++j) o[j] = fmaf(xm, ws6[j], o[j]);
    }
#pragma unroll
    for (int j = 0; j < 6; ++j) {
        float v = o[j];
        for (int off2 = 32; off2; off2 >>= 1) v += __shfl_down(v, off2);
        if (lane == 0) atomicAdd(&acc6[j], v);
    }
    __syncthreads();
    if (t < 6) atomicAdd(&out[b * 6 + t], acc6[t]);
}

// ---------------------------------------------------------------------------
extern "C" void kernel_launch(void* const* d_in, const int* in_sizes, int n_in,
                              void* d_out, int out_size, void* d_ws, size_t ws_size,
                              hipStream_t stream)
{
    (void)in_sizes; (void)n_in; (void)out_size; (void)ws_size;
    const float* X  = (const float*)d_in[0];
    const int*   ei = (const int*)d_in[1];
    const float* Wp = (const float*)d_in[2];
    const float* bp = (const float*)d_in[3];
    const float* Wq = (const float*)d_in[4];
    const float* bq = (const float*)d_in[5];
    const float* Wk = (const float*)d_in[6];
    const float* bk = (const float*)d_in[7];
    const float* Wv = (const float*)d_in[8];
    const float* bv = (const float*)d_in[9];
    const float* Wsk = (const float*)d_in[10];
    const float* bs = (const float*)d_in[11];
    const float* Wr = (const float*)d_in[12];
    const float* br = (const float*)d_in[13];
    float* out = (float*)d_out;

    char* ws = (char*)d_ws;
    u16*   WpT = (u16*)(ws);                                  // 1 MiB
    u16*   WT  = (u16*)(ws + (1u << 20));                     // 512 KiB (q,k)
    float* Mm  = (float*)(ws + 0x1C0000u);                    // 16 KiB
    float* Wsr = (float*)(ws + 0x1C4000u);                    // 6 KiB
    float* Wvr = (float*)(ws + 0x1C8000u);                    // 48 KiB
    u16*   Xp  = (u16*)(ws + (2u << 20));                     // 32 MiB

    // weight transposes (tiled, coalesced both sides) -- Wv no longer needed
    hipLaunchKernelGGL(transpose_cvt, dim3(4, 32), dim3(256), 0, stream,
                       Wp, WpT, 2048, 256);
    hipLaunchKernelGGL(transpose_cvt, dim3(8, 4), dim3(256), 0, stream,
                       Wq, WT, 256, 512);
    hipLaunchKernelGGL(transpose_cvt, dim3(8, 4), dim3(256), 0, stream,
                       Wk, WT + (size_t)512 * 256, 256, 512);
    hipLaunchKernelGGL(prep_small, dim3(17), dim3(256), 0, stream,
                       ei, Wsk, Wv, Wr, bs, bv, br, Mm, Wsr, Wvr, out);
    hipLaunchKernelGGL(gemm1, dim3(1024), dim3(256), 0, stream, X, WpT, bp, Xp);
    hipLaunchKernelGGL(attn, dim3(8192), dim3(256), 0, stream,
                       Xp, WT, Mm, bq, bk, Wvr, Wsr, out);
}

// Round 2
// 907.945 us; speedup vs baseline: 1.1646x; 1.0342x over previous
//
#include <hip/hip_runtime.h>

typedef unsigned short u16;
typedef short bf16x8 __attribute__((ext_vector_type(8)));
typedef float f32x4 __attribute__((ext_vector_type(4)));

__device__ __forceinline__ u16 f2bf(float f) {
    unsigned u = __float_as_uint(f);
    u = (u + 0x7fffu + ((u >> 16) & 1u)) >> 16;
    return (u16)u;
}
__device__ __forceinline__ float bf2f(u16 h) {
    return __uint_as_float(((unsigned)h) << 16);
}
// cheap round-to-nearest pack (a -> low16, b -> high16)
__device__ __forceinline__ unsigned pk2c(float a, float b) {
    return ((__float_as_uint(a) + 0x8000u) >> 16) |
           ((__float_as_uint(b) + 0x8000u) & 0xffff0000u);
}
__device__ __forceinline__ void async16(void* lds, const void* g) {
    __builtin_amdgcn_global_load_lds(
        (const __attribute__((address_space(1))) void*)g,
        (__attribute__((address_space(3))) void*)lds, 16, 0, 0);
}

union U4BF8 { uint4 u; bf16x8 v; };

// ---------------------------------------------------------------------------
// transpose_cvt: dst[c][r] = bf16(src[r][c]); 64x64 LDS tiles, both sides
// coalesced. grid = (C/64, R/64).
// ---------------------------------------------------------------------------
__global__ __launch_bounds__(256) void transpose_cvt(
    const float* __restrict__ src, u16* __restrict__ dst, int R, int C)
{
    __shared__ float tile[64][65];
    const int t = threadIdx.x;
    const int lane = t & 63, wave = t >> 6;
    const int c0 = blockIdx.x * 64, r0 = blockIdx.y * 64;
#pragma unroll
    for (int rr = 0; rr < 16; ++rr) {
        int rl = rr * 4 + wave;
        tile[rl][lane] = src[(size_t)(r0 + rl) * C + c0 + lane];
    }
    __syncthreads();
#pragma unroll
    for (int rr = 0; rr < 16; ++rr) {
        int cl = rr * 4 + wave;
        dst[(size_t)(c0 + cl) * R + r0 + lane] = f2bf(tile[lane][cl]);
    }
}

// ---------------------------------------------------------------------------
// prep_small:
//  blocks 0..7 : Wsr[256][6]   = Ws @ Wr
//  blocks 8..15: Wvr[h][256][6]= Wv_h @ Wr_h
//  block 16    : mask Mm[dst][src] = ln(mult) / -1e30; c0[6] = (bs+bv)@Wr+br
// ---------------------------------------------------------------------------
__global__ __launch_bounds__(256) void prep_small(
    const int* __restrict__ ei, const float* __restrict__ Wsf,
    const float* __restrict__ Wvf, const float* __restrict__ Wr,
    const float* __restrict__ bsf, const float* __restrict__ bvf,
    const float* __restrict__ brf, float* __restrict__ Mm,
    float* __restrict__ Wsr, float* __restrict__ Wvr,
    float* __restrict__ c0)
{
    int t = threadIdx.x, bx = blockIdx.x;
    if (bx < 8) {
        int d = bx * 32 + (t >> 3);
        int os = t & 7;
        float a[6] = {0.f, 0.f, 0.f, 0.f, 0.f, 0.f};
        for (int i = 0; i < 64; ++i) {
            int o = os * 64 + i;
            float w = Wsf[(size_t)d * 512 + o];
#pragma unroll
            for (int j = 0; j < 6; ++j) a[j] += w * Wr[o * 6 + j];
        }
#pragma unroll
        for (int j = 0; j < 6; ++j) {
            a[j] += __shfl_xor(a[j], 1);
            a[j] += __shfl_xor(a[j], 2);
            a[j] += __shfl_xor(a[j], 4);
        }
        if (os == 0) {
#pragma unroll
            for (int j = 0; j < 6; ++j) Wsr[d * 6 + j] = a[j];
        }
    } else if (bx < 16) {
        int d = (bx - 8) * 32 + (t >> 3);
        int hh = t & 7;
        float a[6] = {0.f, 0.f, 0.f, 0.f, 0.f, 0.f};
        for (int i = 0; i < 64; ++i) {
            int o = hh * 64 + i;
            float w = Wvf[(size_t)d * 512 + o];
#pragma unroll
            for (int j = 0; j < 6; ++j) a[j] += w * Wr[o * 6 + j];
        }
#pragma unroll
        for (int j = 0; j < 6; ++j) Wvr[(size_t)(hh * 256 + d) * 6 + j] = a[j];
    } else {
        __shared__ int cnt[4096];
        __shared__ float c6[6];
        for (int i = t; i < 4096; i += 256) cnt[i] = 0;
        if (t < 6) c6[t] = 0.f;
        __syncthreads();
        for (int e = t; e < 1024; e += 256) {
            int s = ei[e];
            int d = ei[1024 + e];
            atomicAdd(&cnt[d * 64 + s], 1);
        }
        __syncthreads();
        for (int i = t; i < 4096; i += 256) {
            int c = cnt[i];
            Mm[i] = (c > 0) ? logf((float)c) : -1e30f;
        }
        float a[6] = {0.f, 0.f, 0.f, 0.f, 0.f, 0.f};
        for (int o = t; o < 512; o += 256) {
            float bb = bsf[o] + bvf[o];
#pragma unroll
            for (int j = 0; j < 6; ++j) a[j] += bb * Wr[o * 6 + j];
        }
#pragma unroll
        for (int j = 0; j < 6; ++j) {
            float v = a[j];
            for (int off = 32; off; off >>= 1) v += __shfl_down(v, off);
            if ((t & 63) == 0) atomicAdd(&c6[j], v);
        }
        __syncthreads();
        if (t < 6) c0[t] = c6[t] + brf[t];
    }
}

// ---------------------------------------------------------------------------
// fused: one block per graph b. Phase 1 = gemm1's 64x256x2048 MFMA tile
// (async global_load_lds staging) -> Xp[b] lives in acc registers; written
// bf16 to LDS Xs[64][264] (row pad 264 -> even bank spread, no swizzle
// needed since writes come from registers). Phase 2 = 8-head attention:
// per head {QK MFMA (B from L2), S MFMA, in-register softmax, colsum ->
// w_all[h]}, mask fragments hoisted to registers once. Phase 3 = single
// t-pass: td[h][d] = sum_src w[h][src]*Xs[src][d] (8 fma per LDS read,
// w reads are wave-uniform broadcasts), skip xbar rides along; contract
// with Wvr/Wsr; 6-wide reduce; out[b] = acc + c0. No Xp global round-trip,
// no atomics on out. LDS union 54.3 KB -> 3 blocks/CU.
// ---------------------------------------------------------------------------
__global__ __launch_bounds__(256, 3) void fused(
    const float* __restrict__ X, const u16* __restrict__ WpT,
    const float* __restrict__ bp, const u16* __restrict__ WT,
    const float* __restrict__ Mm, const float* __restrict__ bq,
    const float* __restrict__ bk, const float* __restrict__ Wvr,
    const float* __restrict__ Wsr, const float* __restrict__ c0,
    float* __restrict__ out)
{
    __shared__ alignas(16) char smem[54304];
    float* As    = (float*)smem;             // gemm stage A [64*36]  (9216 B)
    u16*   Bs    = (u16*)(smem + 9216);      // gemm stage B [256*40] (20480 B)
    u16*   Xs    = (u16*)smem;               // attn [64][264]        (33792 B)
    u16*   Qs    = (u16*)(smem + 33792);     // [64*72]               (9216 B)
    u16*   Ks    = (u16*)(smem + 43008);     // [64*72]               (9216 B)
    float* w_all = (float*)(smem + 52224);   // [8][64]               (2048 B)
    float* acc6  = (float*)(smem + 54272);   // [6]

    const int t = threadIdx.x;
    const int lane = t & 63, wave = t >> 6;
    const int lr = lane & 15, q8 = lane >> 4;
    const int b = blockIdx.x;
    const int m0 = b * 64;
    const f32x4 z4 = {0.f, 0.f, 0.f, 0.f};

    // zero w_all / acc6 (regions untouched by gemm staging)
    w_all[t] = 0.f;
    w_all[256 + t] = 0.f;
    if (t < 6) acc6[t] = 0.f;

    // ================= phase 1: X[b] @ Wp (bf16 MFMA) =================
    // A: 576 chunks of 16 B, c -> row=c/9, part=c%9 (part 8 dup of part 0)
    const int ca0 = t, ca1 = 256 + t, ca2 = 512 + lane;
    const int ra0 = (ca0 * 7282) >> 16, pa0 = ca0 - ra0 * 9;
    const int ra1 = (ca1 * 7282) >> 16, pa1 = ca1 - ra1 * 9;
    const int ra2 = (ca2 * 7282) >> 16, pa2 = ca2 - ra2 * 9;
    const float* pA0 = X + (size_t)(m0 + ra0) * 2048 + (pa0 == 8 ? 0 : pa0 * 4);
    const float* pA1 = X + (size_t)(m0 + ra1) * 2048 + (pa1 == 8 ? 0 : pa1 * 4);
    const float* pA2 = X + (size_t)(m0 + ra2) * 2048 + (pa2 == 8 ? 0 : pa2 * 4);
    // B: 1280 chunks of 16 B, c -> n=c/5, part=c%5 (part 4 dup of part 0)
    const u16* pB[5];
#pragma unroll
    for (int i = 0; i < 5; ++i) {
        int c = i * 256 + t;
        int n = (c * 13108) >> 16;
        int prt = c - n * 5;
        pB[i] = WpT + (size_t)n * 2048 + (prt == 4 ? 0 : prt * 8);
    }

    f32x4 acc[16];
#pragma unroll
    for (int j = 0; j < 16; ++j) acc[j] = z4;

    const int arow = (wave * 16 + lr) * 36 + q8 * 8;

    for (int kk = 0; kk < 64; ++kk) {
        const int k0 = kk * 32;
        async16(&As[(size_t)ca0 * 4], pA0 + k0);
        async16(&As[(size_t)ca1 * 4], pA1 + k0);
        if (wave == 0) async16(&As[(size_t)ca2 * 4], pA2 + k0);
#pragma unroll
        for (int i = 0; i < 5; ++i)
            async16(&Bs[(size_t)(i * 256 + t) * 8], pB[i] + k0);
        __syncthreads();
        const float4 af0 = *(const float4*)&As[arow];
        const float4 af1 = *(const float4*)&As[arow + 4];
        U4BF8 ua;
        ua.u.x = pk2c(af0.x, af0.y);
        ua.u.y = pk2c(af0.z, af0.w);
        ua.u.z = pk2c(af1.x, af1.y);
        ua.u.w = pk2c(af1.z, af1.w);
        const bf16x8 a = ua.v;
#pragma unroll
        for (int j = 0; j < 16; ++j) {
            const bf16x8 bfrag = *(const bf16x8*)&Bs[(j * 16 + lr) * 40 + q8 * 8];
            acc[j] = __builtin_amdgcn_mfma_f32_16x16x32_bf16(a, bfrag, acc[j], 0, 0, 0);
        }
        __syncthreads();
    }

    // ---- epilogue: Xp[b] -> Xs bf16, rows padded to 264 u16 ----
#pragma unroll
    for (int j = 0; j < 16; ++j) {
        const int col = j * 16 + lr;
        const float bias = bp[col];
#pragma unroll
        for (int r = 0; r < 4; ++r) {
            int row = wave * 16 + q8 * 4 + r;
            Xs[row * 264 + col] = f2bf(acc[j][r] + bias);
        }
    }
    __syncthreads();

    // ================= phase 2: 8-head attention =================
    const int dst0 = wave * 16 + q8 * 4;
    float mreg[4][4];
#pragma unroll
    for (int r2 = 0; r2 < 4; ++r2)
#pragma unroll
        for (int j = 0; j < 4; ++j)
            mreg[r2][j] = Mm[(dst0 + r2) * 64 + j * 16 + lr];

    const int jj0 = wave * 2;
    for (int h = 0; h < 8; ++h) {
        // --- QK GEMM: 8 col-tiles of 16 (q0-3, k4-7); wave owns 2
        f32x4 qacc[2][4];
#pragma unroll
        for (int jt = 0; jt < 2; ++jt)
#pragma unroll
            for (int i = 0; i < 4; ++i) qacc[jt][i] = z4;
#pragma unroll 2
        for (int kk = 0; kk < 8; ++kk) {
            bf16x8 af[4];
#pragma unroll
            for (int i = 0; i < 4; ++i)
                af[i] = *(const bf16x8*)&Xs[(i * 16 + lr) * 264 + (kk * 4 + q8) * 8];
#pragma unroll
            for (int jt = 0; jt < 2; ++jt) {
                int jj = jj0 + jt, sec = jj >> 2;
                int r = sec * 512 + h * 64 + (jj & 3) * 16 + lr;
                bf16x8 bfv = *(const bf16x8*)(WT + (size_t)r * 256 + kk * 32 + q8 * 8);
#pragma unroll
                for (int i = 0; i < 4; ++i)
                    qacc[jt][i] = __builtin_amdgcn_mfma_f32_16x16x32_bf16(
                        af[i], bfv, qacc[jt][i], 0, 0, 0);
            }
        }
        // epilogue -> LDS (pad 72); q scaled 1/8 w/ bias, k w/ bias
#pragma unroll
        for (int jt = 0; jt < 2; ++jt) {
            int jj = jj0 + jt, sec = jj >> 2;
            int colh = (jj & 3) * 16 + lr;
            float bias = (sec == 0) ? bq[h * 64 + colh] : bk[h * 64 + colh];
#pragma unroll
            for (int i = 0; i < 4; ++i)
#pragma unroll
                for (int r2 = 0; r2 < 4; ++r2) {
                    int row = i * 16 + q8 * 4 + r2;
                    float v = qacc[jt][i][r2] + bias;
                    if (sec == 0) Qs[row * 72 + colh] = f2bf(v * 0.125f);
                    else          Ks[row * 72 + colh] = f2bf(v);
                }
        }
        __syncthreads();

        // --- S-MFMA: wave owns dst rows wave*16..+15
        f32x4 sacc[4];
#pragma unroll
        for (int j = 0; j < 4; ++j) sacc[j] = z4;
#pragma unroll
        for (int k2 = 0; k2 < 2; ++k2) {
            bf16x8 aq = *(const bf16x8*)&Qs[(wave * 16 + lr) * 72 + k2 * 32 + q8 * 8];
#pragma unroll
            for (int j = 0; j < 4; ++j) {
                bf16x8 bk8 = *(const bf16x8*)&Ks[(j * 16 + lr) * 72 + k2 * 32 + q8 * 8];
                sacc[j] = __builtin_amdgcn_mfma_f32_16x16x32_bf16(aq, bk8, sacc[j], 0, 0, 0);
            }
        }
        // --- mask + in-register softmax (rows in C layout)
        float p[4][4];
#pragma unroll
        for (int r2 = 0; r2 < 4; ++r2) {
            float m = -1e38f;
#pragma unroll
            for (int j = 0; j < 4; ++j) {
                sacc[j][r2] += mreg[r2][j];
                m = fmaxf(m, sacc[j][r2]);
            }
            m = fmaxf(m, __shfl_xor(m, 1));
            m = fmaxf(m, __shfl_xor(m, 2));
            m = fmaxf(m, __shfl_xor(m, 4));
            m = fmaxf(m, __shfl_xor(m, 8));
            bool dead = (m < -1e29f);
            float rs = 0.f;
#pragma unroll
            for (int j = 0; j < 4; ++j) {
                float pv = dead ? 0.f : __expf(sacc[j][r2] - m);
                p[j][r2] = pv;
                rs += pv;
            }
            rs += __shfl_xor(rs, 1);
            rs += __shfl_xor(rs, 2);
            rs += __shfl_xor(rs, 4);
            rs += __shfl_xor(rs, 8);
            float sc = 1.0f / (rs + 1e-16f) * (1.0f / 64.0f);
#pragma unroll
            for (int j = 0; j < 4; ++j) p[j][r2] *= sc;
        }
        // --- column sums -> w_all[h]
#pragma unroll
        for (int j = 0; j < 4; ++j) {
            float cw = p[j][0] + p[j][1] + p[j][2] + p[j][3];
            cw += __shfl_xor(cw, 16);
            cw += __shfl_xor(cw, 32);
            if (lane < 16) atomicAdd(&w_all[h * 64 + j * 16 + lr], cw);
        }
        __syncthreads();
    }

    // ================= phase 3: t-pass + output =================
    float td[8] = {0.f, 0.f, 0.f, 0.f, 0.f, 0.f, 0.f, 0.f};
    float xb = 0.f;
    const int d = t;
#pragma unroll 4
    for (int src = 0; src < 64; ++src) {
        float xv = bf2f(Xs[src * 264 + d]);   // lanes read consecutive d: free
        xb += xv;
#pragma unroll
        for (int h = 0; h < 8; ++h)           // wave-uniform broadcast reads
            td[h] = fmaf(w_all[h * 64 + src], xv, td[h]);
    }
    float o[6];
    {
        float xm = xb * (1.0f / 64.0f);
        const float* ws6 = Wsr + d * 6;
#pragma unroll
        for (int j = 0; j < 6; ++j) o[j] = xm * ws6[j];
    }
#pragma unroll
    for (int h = 0; h < 8; ++h) {
        const float* wv = Wvr + (size_t)(h * 256 + d) * 6;
#pragma unroll
        for (int j = 0; j < 6; ++j) o[j] = fmaf(td[h], wv[j], o[j]);
    }
#pragma unroll
    for (int j = 0; j < 6; ++j) {
        float v = o[j];
        for (int off2 = 32; off2; off2 >>= 1) v += __shfl_down(v, off2);
        if (lane == 0) atomicAdd(&acc6[j], v);
    }
    __syncthreads();
    if (t < 6) out[b * 6 + t] = acc6[t] + c0[t];
}

// ---------------------------------------------------------------------------
extern "C" void kernel_launch(void* const* d_in, const int* in_sizes, int n_in,
                              void* d_out, int out_size, void* d_ws, size_t ws_size,
                              hipStream_t stream)
{
    (void)in_sizes; (void)n_in; (void)out_size; (void)ws_size;
    const float* X  = (const float*)d_in[0];
    const int*   ei = (const int*)d_in[1];
    const float* Wp = (const float*)d_in[2];
    const float* bp = (const float*)d_in[3];
    const float* Wq = (const float*)d_in[4];
    const float* bq = (const float*)d_in[5];
    const float* Wk = (const float*)d_in[6];
    const float* bk = (const float*)d_in[7];
    const float* Wv = (const float*)d_in[8];
    const float* bv = (const float*)d_in[9];
    const float* Wsk = (const float*)d_in[10];
    const float* bs = (const float*)d_in[11];
    const float* Wr = (const float*)d_in[12];
    const float* br = (const float*)d_in[13];
    float* out = (float*)d_out;

    char* ws = (char*)d_ws;
    u16*   WpT = (u16*)(ws);                                  // 1 MiB
    u16*   WT  = (u16*)(ws + (1u << 20));                     // 512 KiB (q,k)
    float* Mm  = (float*)(ws + 0x180000u);                    // 16 KiB
    float* Wsr = (float*)(ws + 0x184000u);                    // 6 KiB
    float* Wvr = (float*)(ws + 0x188000u);                    // 48 KiB
    float* c0  = (float*)(ws + 0x194000u);                    // 24 B

    hipLaunchKernelGGL(transpose_cvt, dim3(4, 32), dim3(256), 0, stream,
                       Wp, WpT, 2048, 256);
    hipLaunchKernelGGL(transpose_cvt, dim3(8, 4), dim3(256), 0, stream,
                       Wq, WT, 256, 512);
    hipLaunchKernelGGL(transpose_cvt, dim3(8, 4), dim3(256), 0, stream,
                       Wk, WT + (size_t)512 * 256, 256, 512);
    hipLaunchKernelGGL(prep_small, dim3(17), dim3(256), 0, stream,
                       ei, Wsk, Wv, Wr, bs, bv, br, Mm, Wsr, Wvr, c0);
    hipLaunchKernelGGL(fused, dim3(1024), dim3(256), 0, stream,
                       X, WpT, bp, WT, Mm, bq, bk, Wvr, Wsr, c0, out);
}